// Round 3
// baseline (3264.803 us; speedup 1.0000x reference)
//
#include <hip/hip_runtime.h>

#define T_STEPS 4096
#define BATCH   64
#define INDIM   4
#define H       256
#define OUTD    2
#define NCOL    16                    // batch columns per block
#define CHUNK   32                    // steps of x staged per refill
#define COL_DW  136                   // 544 B per col per slot (512 data + 32 skew)
#define SLOT_DW (NCOL*COL_DW)         // 2176 dwords per h slot
#define XS_DW   (CHUNK*256)           // [s][c][16 dw]: 32 f16 lane-padded per col
#define LDS_DW  (2*SLOT_DW + XS_DW)   // 12544 dw = 50.2 KB

typedef _Float16 h8  __attribute__((ext_vector_type(8)));
typedef float    f4  __attribute__((ext_vector_type(4)));

__device__ __forceinline__ unsigned pk(float a, float b) {
    return __builtin_bit_cast(unsigned, __builtin_amdgcn_cvt_pkrtz(a, b));
}

__device__ __forceinline__ float fast_tanh(float x) {
    float ax = fabsf(x);
    float e  = __expf(-2.0f * ax);
    float r  = (1.0f - e) * __builtin_amdgcn_rcpf(1.0f + e);
    return copysignf(r, x);
}

// MFMA rewrite. fdot2 is half-rate (R2: VALUBusy 63% on active CUs = 2x the
// static 2cy count) so any fdot2 layout floors at ~512cy/SIMD/step. MFMA
// 16x16x32_f16 does the same 256x256 matvec for SIXTEEN batches in 36
// MFMA/wave (~180cy). h lives in a double-buffered LDS slot, layout
// [col][kt][g][e] so B-fragments are single b128 reads; Wh + Wi + biases are
// folded into 9 resident A K-tiles (9th = [Wi | bi+bh] vs B = [x | 1.0]).
// Output head = 1 extra M-tile on a rotating wave reusing this step's
// B-frags (no ring, no deferred pass). k-permutation inside a frag is
// self-canceling since A and B use identical packing.
__global__ __attribute__((amdgpu_waves_per_eu(1, 1))) __launch_bounds__(256)
void elman_kernel(const float* __restrict__ input,
                  const float* __restrict__ Wi,
                  const float* __restrict__ bi,
                  const float* __restrict__ Wh,
                  const float* __restrict__ bh,
                  const float* __restrict__ Wf,
                  const float* __restrict__ bf,
                  float* __restrict__ out)
{
    const int t    = threadIdx.x;
    const int w    = t >> 6;          // wave 0..3 -> rows 64w..64w+63
    const int lane = t & 63;
    const int c    = lane & 15;       // batch col within block
    const int g    = lane >> 4;       // k-group 0..3
    const int b0   = blockIdx.x * NCOL;

    __shared__ unsigned lds[LDS_DW];
    unsigned* xs = lds + 2 * SLOT_DW;

    // ---- resident A fragments: Wh rows w*64+mt*16+c, k = kt*32+g*8+e ----
    h8 a[4][9];
    #pragma unroll
    for (int mt = 0; mt < 4; ++mt) {
        const int row = w * 64 + mt * 16 + c;
        #pragma unroll
        for (int kt = 0; kt < 8; ++kt) {
            const float* p = Wh + (size_t)row * H + kt * 32 + g * 8;
            float4 x0 = *(const float4*)(p);
            float4 x1 = *(const float4*)(p + 4);
            uint4 u;
            u.x = pk(x0.x, x0.y); u.y = pk(x0.z, x0.w);
            u.z = pk(x1.x, x1.y); u.w = pk(x1.z, x1.w);
            a[mt][kt] = __builtin_bit_cast(h8, u);
        }
        // 9th K-tile: [Wi | bias] against B = [x | 1.0]
        uint4 u = {0u, 0u, 0u, 0u};
        if (g == 0) {
            float4 wi = *(const float4*)(Wi + row * INDIM);
            u.x = pk(wi.x, wi.y);
            u.y = pk(wi.z, wi.w);
            u.z = pk(bi[row] + bh[row], 0.f);
        }
        a[mt][8] = __builtin_bit_cast(h8, u);
    }
    // head A fragments: Wf rows 0..1 in M-rows 0..1, rest zero
    h8 awf[8];
    #pragma unroll
    for (int kt = 0; kt < 8; ++kt) {
        uint4 u = {0u, 0u, 0u, 0u};
        if (c < OUTD) {
            const float* p = Wf + (size_t)c * H + kt * 32 + g * 8;
            float4 x0 = *(const float4*)(p);
            float4 x1 = *(const float4*)(p + 4);
            u.x = pk(x0.x, x0.y); u.y = pk(x0.z, x0.w);
            u.z = pk(x1.x, x1.y); u.w = pk(x1.z, x1.w);
        }
        awf[kt] = __builtin_bit_cast(h8, u);
    }
    const float bf0 = bf[0], bf1 = bf[1];

    // ---- init: zero h slot 0 (= h_{-1}) and xstage; plant 1.0 slots ----
    for (int idx = t; idx < SLOT_DW; idx += 256) lds[idx] = 0u;
    for (int idx = t; idx < XS_DW; idx += 256) xs[idx] = 0u;
    #pragma unroll
    for (int it = 0; it < 2; ++it) {
        const int task = t + it * 256;          // 512 tasks: [s][c]
        xs[(task >> 4) * 256 + (task & 15) * 16 + 2] = 0x00003C00u; // f16 1.0
    }
    __syncthreads();

    const int rdw = c * COL_DW + g * 4;         // B-read dword base within slot

    #pragma unroll 2
    for (int i = 0; i < T_STEPS; ++i) {
        if ((i & (CHUNK - 1)) == 0) {
            // refill xstage for steps i..i+31 (only VMEM reads in loop)
            #pragma unroll
            for (int it = 0; it < 2; ++it) {
                const int task = t + it * 256;
                const int s = task >> 4, cc = task & 15;
                float4 xv = *(const float4*)(input +
                    ((size_t)(i + s) * BATCH + b0 + cc) * INDIM);
                uint2 pkd = { pk(xv.x, xv.y), pk(xv.z, xv.w) };
                *(uint2*)(xs + s * 256 + cc * 16) = pkd;
            }
            __syncthreads();
        }

        // ---- B fragments: h_{i-1} (slot i&1) + x-tile ----
        const unsigned* hb = lds + (i & 1) * SLOT_DW;
        h8 bfr[9];
        #pragma unroll
        for (int kt = 0; kt < 8; ++kt) {
            uint4 u = *(const uint4*)(hb + rdw + kt * 16);
            bfr[kt] = __builtin_bit_cast(h8, u);
        }
        {
            uint4 u = *(const uint4*)(xs + (i & (CHUNK - 1)) * 256 + c * 16 + g * 4);
            bfr[8] = __builtin_bit_cast(h8, u);
        }

        // ---- rotating output head: out[i-1] from h_{i-1} ----
        if (i && ((i & 3) == w)) {
            f4 dh = {0.f, 0.f, 0.f, 0.f};
            #pragma unroll
            for (int kt = 0; kt < 8; ++kt)
                dh = __builtin_amdgcn_mfma_f32_16x16x32_f16(awf[kt], bfr[kt], dh, 0, 0, 0);
            if (g == 0) {
                float2 o2 = { fast_tanh(dh.x + bf0), fast_tanh(dh.y + bf1) };
                *(float2*)(out + ((size_t)(i - 1) * BATCH + b0 + c) * OUTD) = o2;
            }
        }

        // ---- recurrence: D = [Wh|Wi|bias] x [h;x;1] ----
        f4 d0 = {0.f,0.f,0.f,0.f}, d1 = d0, d2 = d0, d3 = d0;
        #pragma unroll
        for (int kt = 0; kt < 9; ++kt) {
            d0 = __builtin_amdgcn_mfma_f32_16x16x32_f16(a[0][kt], bfr[kt], d0, 0, 0, 0);
            d1 = __builtin_amdgcn_mfma_f32_16x16x32_f16(a[1][kt], bfr[kt], d1, 0, 0, 0);
            d2 = __builtin_amdgcn_mfma_f32_16x16x32_f16(a[2][kt], bfr[kt], d2, 0, 0, 0);
            d3 = __builtin_amdgcn_mfma_f32_16x16x32_f16(a[3][kt], bfr[kt], d3, 0, 0, 0);
        }

        // ---- tanh + pack + store h_i into slot (i&1)^1 ----
        unsigned* wsl = lds + ((i & 1) ^ 1) * SLOT_DW;
        f4 dd[4] = {d0, d1, d2, d3};
        #pragma unroll
        for (int mt = 0; mt < 4; ++mt) {
            float h0 = fast_tanh(dd[mt].x);
            float h1 = fast_tanh(dd[mt].y);
            float h2 = fast_tanh(dd[mt].z);
            float h3 = fast_tanh(dd[mt].w);
            const int r = w * 64 + mt * 16 + g * 4;   // rows r..r+3, col c
            const int dwo = c * COL_DW + ((r >> 5) << 4) + (((r >> 3) & 3) << 2)
                          + ((g & 1) << 1);
            uint2 ph = { pk(h0, h1), pk(h2, h3) };
            *(uint2*)(wsl + dwo) = ph;
        }
        __syncthreads();
    }

    // ---- final head: out[4095] from h_4095 (slot 0) ----
    if (w == 0) {
        const unsigned* hb = lds;                 // slot 4096&1 = 0
        f4 dh = {0.f, 0.f, 0.f, 0.f};
        #pragma unroll
        for (int kt = 0; kt < 8; ++kt) {
            uint4 u = *(const uint4*)(hb + rdw + kt * 16);
            dh = __builtin_amdgcn_mfma_f32_16x16x32_f16(awf[kt],
                     __builtin_bit_cast(h8, u), dh, 0, 0, 0);
        }
        if (g == 0) {
            float2 o2 = { fast_tanh(dh.x + bf0), fast_tanh(dh.y + bf1) };
            *(float2*)(out + ((size_t)(T_STEPS - 1) * BATCH + b0 + c) * OUTD) = o2;
        }
    }
}

extern "C" void kernel_launch(void* const* d_in, const int* in_sizes, int n_in,
                              void* d_out, int out_size, void* d_ws, size_t ws_size,
                              hipStream_t stream) {
    const float* input = (const float*)d_in[0];
    // d_in[1] = target (unused by forward)
    const float* Wi = (const float*)d_in[2];
    const float* bi = (const float*)d_in[3];
    const float* Wh = (const float*)d_in[4];
    const float* bh = (const float*)d_in[5];
    const float* Wf = (const float*)d_in[6];
    const float* bf = (const float*)d_in[7];
    float* out = (float*)d_out;

    elman_kernel<<<dim3(BATCH / NCOL), dim3(256), 0, stream>>>(
        input, Wi, bi, Wh, bh, Wf, bf, out);
}